// Round 6
// baseline (311.375 us; speedup 1.0000x reference)
//
#include <hip/hip_runtime.h>
#include <math.h>

typedef unsigned short ushort_t;
typedef __bf16 bf16x8 __attribute__((ext_vector_type(8)));
typedef ushort_t ushort8v __attribute__((ext_vector_type(8)));
typedef float f32x4 __attribute__((ext_vector_type(4)));

#define B_SZ   4
#define SEQ    8192
#define M_ROWS 32768
#define CH     32
#define NC     256          // sub-chunks (32 rows) per sequence
#define SSTR   136          // gemm1 LDS scanbuf row stride (ushorts); 16B-aligned rows, 68%32=4 bank shift
#define FSTR   132          // gemm2 LDS fscan row stride (floats);   16B-aligned rows, 132%32=4

__device__ __forceinline__ ushort_t f2bf(float f) {
    unsigned u = __float_as_uint(f);
    u = u + 0x7fffu + ((u >> 16) & 1u);
    return (ushort_t)(u >> 16);
}
__device__ __forceinline__ float bf2f(ushort_t b) {
    return __uint_as_float(((unsigned)b) << 16);
}

__device__ __forceinline__ void load16_lds(const void* g, void* l) {
    __builtin_amdgcn_global_load_lds(
        (const __attribute__((address_space(1))) unsigned int*)g,
        (__attribute__((address_space(3))) unsigned int*)l, 16, 0, 0);
}

// ---------------------------------------------------------------------------
// Fused: x -> X16 bf16 convert (all 16384 blocks) + param/B/C prep (blocks<1024)
__global__ __launch_bounds__(256)
void prep_conv(const float* __restrict__ x, ushort_t* __restrict__ X16,
               const float* __restrict__ Lre, const float* __restrict__ Lim,
               const float* __restrict__ ldt,
               const float* __restrict__ Bre, const float* __restrict__ Bim,
               const float* __restrict__ Cre, const float* __restrict__ Cim,
               float* __restrict__ abar, float* __restrict__ apow,
               ushort_t* __restrict__ Bmat, ushort_t* __restrict__ Cmat) {
    int i = blockIdx.x * 256 + threadIdx.x;
    float4 v = ((const float4*)x)[i];
    ushort_t o[4] = {f2bf(v.x), f2bf(v.y), f2bf(v.z), f2bf(v.w)};
    *(uint2*)&X16[(size_t)i * 4] = *(const uint2*)o;

    if (blockIdx.x < 1024) {
        int idx = i;                        // 0 .. 262143
        int h = idx & 511;
        int p = (idx >> 9) & 255;
        int d = idx >> 17;
        int ip = d * 256 + p;
        float lr = Lre[ip], li = Lim[ip];
        float dt = expf(ldt[ip]);
        float e   = expf(lr * dt);
        float ang = li * dt;
        float ar = e * cosf(ang), ai = e * sinf(ang);
        float nr = ar - 1.0f, ni = ai;
        float den = lr * lr + li * li;
        float cr = (nr * lr + ni * li) / den;
        float ci = (ni * lr - nr * li) / den;
        float br = Bre[idx], bi = Bim[idx];
        Bmat[(d * 512 + 2 * p) * 512 + h]     = f2bf(cr * br - ci * bi);
        Bmat[(d * 512 + 2 * p + 1) * 512 + h] = f2bf(cr * bi + ci * br);
        if (h == 0) {
            int oo = d * 512 + 2 * p;
            abar[oo] = ar;  abar[oo + 1] = ai;
            float eC = expf(lr * dt * (float)CH);
            float aC = ang * (float)CH;
            apow[oo] = eC * cosf(aC);  apow[oo + 1] = eC * sinf(aC);
        }
        int p2 = idx & 255;
        int h2 = (idx >> 8) & 511;
        int d2 = idx >> 17;
        Cmat[h2 * 1024 + d2 * 512 + 2 * p2]     = f2bf(Cre[idx]);
        Cmat[h2 * 1024 + d2 * 512 + 2 * p2 + 1] = f2bf(-Cim[idx]);
    }
}

// ---------------------------------------------------------------------------
// GEMM1: SB[M][1024] = X16[M][512] * Bmat[1024][512]^T, bf16 MFMA.
// Epilogue: acc -> LDS (row-major, SSTR pad) -> coalesced 16B SB stores,
// plus 4 per-sub-chunk carries per channel computed from LDS -> carry buf.
__global__ __launch_bounds__(256)
void gemm1_mfma(const ushort_t* __restrict__ A, const ushort_t* __restrict__ Bm,
                ushort_t* __restrict__ SB, const float* __restrict__ abar,
                float* __restrict__ carry) {
    __shared__ __align__(16) char lds[128 * SSTR * 2];   // 34816 B
    ushort_t* As = (ushort_t*)lds;                       // 8 KB (K loop)
    ushort_t* Bs = (ushort_t*)(lds + 8192);              // 8 KB (K loop)
    ushort_t* scanbuf = (ushort_t*)lds;                  // 34 KB (epilogue)

    const int tid  = threadIdx.x;
    const int lane = tid & 63;
    const int wv   = tid >> 6;
    const int wrow = wv >> 1, wcol = wv & 1;
    const int l15  = lane & 15, lq = lane >> 4;

    const int lin = blockIdx.x;
    const int xcd = lin & 7;
    const int j   = lin >> 3;
    const int mt  = xcd * 32 + (j >> 3);
    const int nt  = j & 7;
    const int m0 = mt * 128;
    const int n0 = nt * 128;

    f32x4 acc[4][4];
#pragma unroll
    for (int i = 0; i < 4; ++i)
#pragma unroll
        for (int jj = 0; jj < 4; ++jj)
            acc[i][jj] = (f32x4){0.f, 0.f, 0.f, 0.f};

    const int grow_l = lane >> 2;
    const int gk8    = (lane & 3) * 8;
    const ushort_t* aF = As + (wrow * 64 + l15) * 32 + lq * 8;
    const ushort_t* bF = Bs + (wcol * 64 + l15) * 32 + lq * 8;

    for (int kt = 0; kt < 512; kt += 32) {
        __syncthreads();
#pragma unroll
        for (int j2 = 0; j2 < 2; ++j2) {
            const int r0 = j2 * 64 + wv * 16;
            load16_lds(&A[(size_t)(m0 + r0 + grow_l) * 512 + kt + gk8],
                       (void*)&As[r0 * 32]);
            load16_lds(&Bm[(size_t)(n0 + r0 + grow_l) * 512 + kt + gk8],
                       (void*)&Bs[r0 * 32]);
        }
        __syncthreads();

        bf16x8 af[4], bfr[4];
#pragma unroll
        for (int mi = 0; mi < 4; ++mi) {
            union { ushort8v u; bf16x8 b; } cv;
            cv.u = *(const ushort8v*)(aF + mi * 512);
            af[mi] = cv.b;
        }
#pragma unroll
        for (int ni = 0; ni < 4; ++ni) {
            union { ushort8v u; bf16x8 b; } cv;
            cv.u = *(const ushort8v*)(bF + ni * 512);
            bfr[ni] = cv.b;
        }
#pragma unroll
        for (int mi = 0; mi < 4; ++mi)
#pragma unroll
            for (int ni = 0; ni < 4; ++ni)
                acc[mi][ni] = __builtin_amdgcn_mfma_f32_16x16x32_bf16(
                    af[mi], bfr[ni], acc[mi][ni], 0, 0, 0);
    }

    // ---- epilogue: transpose to LDS
    __syncthreads();
#pragma unroll
    for (int mi = 0; mi < 4; ++mi)
#pragma unroll
        for (int ni = 0; ni < 4; ++ni) {
            const int col = wcol * 64 + ni * 16 + l15;
#pragma unroll
            for (int r = 0; r < 4; ++r) {
                const int row = wrow * 64 + mi * 16 + lq * 4 + r;
                scanbuf[row * SSTR + col] = f2bf(acc[mi][ni][r]);
            }
        }
    __syncthreads();

    // ---- coalesced SB store: thread -> (row, half-row of 64 cols)
    {
        const int row = tid >> 1, hf = tid & 1;
        const ushort_t* src = scanbuf + row * SSTR + hf * 64;
        ushort_t* dst = SB + (size_t)(m0 + row) * 1024 + n0 + hf * 64;
        const int rot = ((row >> 3) << 1) & 7;   // spread LDS banks across rows
#pragma unroll
        for (int q0 = 0; q0 < 8; ++q0) {
            int q = (q0 + rot) & 7;
            *(ushort8v*)(dst + q * 8) = *(const ushort8v*)(src + q * 8);
        }
    }

    // ---- sub-chunk carries: 64 channels x 4 segments of 32 rows
    {
        const int ch = tid & 63, sg = tid >> 6;
        const int pg = (n0 >> 1) + ch;
        const bool bwd = (n0 >= 512);
        const float ar = abar[2 * pg], ai = abar[2 * pg + 1];
        float sr = 0.f, si = 0.f;
#pragma unroll 8
        for (int i2 = 0; i2 < 32; ++i2) {
            const int row = sg * 32 + (bwd ? 31 - i2 : i2);
            unsigned u = *(const unsigned*)&scanbuf[row * SSTR + 2 * ch];
            float re = bf2f((ushort_t)(u & 0xffffu));
            float im = bf2f((ushort_t)(u >> 16));
            float nr = fmaf(ar, sr, fmaf(-ai, si, re));
            float ni = fmaf(ar, si, fmaf(ai, sr, im));
            sr = nr; si = ni;
        }
        const int ms = (m0 >> 5) + sg;           // global sub-chunk id
        carry[ms * 1024 + 2 * pg]     = sr;
        carry[ms * 1024 + 2 * pg + 1] = si;
    }
}

// ---------------------------------------------------------------------------
__global__ __launch_bounds__(512)
void scan_comb(const float* __restrict__ carry, float* __restrict__ init,
               const float* __restrict__ apow) {
    int b = blockIdx.x, t = threadIdx.x;
    int dir = t >> 8, p = t & 255;
    float pr = apow[dir * 512 + 2 * p], pi = apow[dir * 512 + 2 * p + 1];
    float sr = 0.f, si = 0.f;
#pragma unroll 8
    for (int cc = 0; cc < NC; ++cc) {
        int c = dir ? (NC - 1 - cc) : cc;
        int o = (b * NC + c) * 1024 + dir * 512 + 2 * p;
        init[o] = sr; init[o + 1] = si;
        float cr = carry[o], ci = carry[o + 1];
        float nr = fmaf(pr, sr, fmaf(-pi, si, cr));
        float ni = fmaf(pr, si, fmaf(pi, sr, ci));
        sr = nr; si = ni;
    }
}

__global__ __launch_bounds__(512)
void scan_final(ushort_t* __restrict__ S, const float* __restrict__ abar,
                const float* __restrict__ init) {
    int b = blockIdx.x, c = blockIdx.y, t = threadIdx.x;
    int dir = t >> 8, p = t & 255;
    float ar = abar[dir * 512 + 2 * p], ai = abar[dir * 512 + 2 * p + 1];
    int o = (b * NC + c) * 1024 + dir * 512 + 2 * p;
    float sr = init[o], si = init[o + 1];
    ushort_t* base = S + ((size_t)b * SEQ + (size_t)c * CH) * 1024
                       + dir * 512 + 2 * p;
    for (int batch = 0; batch < CH; batch += 8) {
        unsigned v[8];
#pragma unroll
        for (int q = 0; q < 8; ++q) {
            int l = batch + q;
            int row = dir ? (CH - 1 - l) : l;
            v[q] = *(const unsigned*)(base + (size_t)row * 1024);
        }
#pragma unroll
        for (int q = 0; q < 8; ++q) {
            float re = bf2f((ushort_t)(v[q] & 0xffffu));
            float im = bf2f((ushort_t)(v[q] >> 16));
            float nr = fmaf(ar, sr, fmaf(-ai, si, re));
            float ni = fmaf(ar, si, fmaf(ai, sr, im));
            sr = nr; si = ni;
            v[q] = ((unsigned)f2bf(si) << 16) | (unsigned)f2bf(sr);
        }
#pragma unroll
        for (int q = 0; q < 8; ++q) {
            int l = batch + q;
            int row = dir ? (CH - 1 - l) : l;
            *(unsigned*)(base + (size_t)row * 1024) = v[q];
        }
    }
}

// ---------------------------------------------------------------------------
// GEMM2: y[M][512] = SB[M][1024] * Cmat[512][1024]^T + x*(D0+D1).
// Epilogue: two 64-row halves through LDS -> coalesced 16B fp32 stores.
__global__ __launch_bounds__(256)
void gemm2_mfma(const ushort_t* __restrict__ A, const ushort_t* __restrict__ Bm,
                float* __restrict__ y, const float* __restrict__ X,
                const float* __restrict__ Dv) {
    __shared__ __align__(16) char lds[34816];
    ushort_t* As = (ushort_t*)lds;
    ushort_t* Bs = (ushort_t*)(lds + 8192);
    float* fscan = (float*)lds;                 // 64*FSTR*4 = 33792 B
    float* dsum  = (float*)(lds + 33792);       // 128 floats (above As/Bs 16KB)

    const int tid  = threadIdx.x;
    const int lane = tid & 63;
    const int wv   = tid >> 6;
    const int wrow = wv >> 1, wcol = wv & 1;
    const int l15  = lane & 15, lq = lane >> 4;

    const int lin = blockIdx.x;
    const int xcd = lin & 7;
    const int j   = lin >> 3;
    const int mt  = xcd * 32 + (j >> 2);
    const int nt  = j & 3;
    const int m0 = mt * 128;
    const int n0 = nt * 128;

    if (tid < 128) dsum[tid] = Dv[n0 + tid] + Dv[512 + n0 + tid];

    f32x4 acc[4][4];
#pragma unroll
    for (int i = 0; i < 4; ++i)
#pragma unroll
        for (int jj = 0; jj < 4; ++jj)
            acc[i][jj] = (f32x4){0.f, 0.f, 0.f, 0.f};

    const int grow_l = lane >> 2;
    const int gk8    = (lane & 3) * 8;
    const ushort_t* aF = As + (wrow * 64 + l15) * 32 + lq * 8;
    const ushort_t* bF = Bs + (wcol * 64 + l15) * 32 + lq * 8;

    for (int kt = 0; kt < 1024; kt += 32) {
        __syncthreads();
#pragma unroll
        for (int j2 = 0; j2 < 2; ++j2) {
            const int r0 = j2 * 64 + wv * 16;
            load16_lds(&A[(size_t)(m0 + r0 + grow_l) * 1024 + kt + gk8],
                       (void*)&As[r0 * 32]);
            load16_lds(&Bm[(size_t)(n0 + r0 + grow_l) * 1024 + kt + gk8],
                       (void*)&Bs[r0 * 32]);
        }
        __syncthreads();

        bf16x8 af[4], bfr[4];
#pragma unroll
        for (int mi = 0; mi < 4; ++mi) {
            union { ushort8v u; bf16x8 b; } cv;
            cv.u = *(const ushort8v*)(aF + mi * 512);
            af[mi] = cv.b;
        }
#pragma unroll
        for (int ni = 0; ni < 4; ++ni) {
            union { ushort8v u; bf16x8 b; } cv;
            cv.u = *(const ushort8v*)(bF + ni * 512);
            bfr[ni] = cv.b;
        }
#pragma unroll
        for (int mi = 0; mi < 4; ++mi)
#pragma unroll
            for (int ni = 0; ni < 4; ++ni)
                acc[mi][ni] = __builtin_amdgcn_mfma_f32_16x16x32_bf16(
                    af[mi], bfr[ni], acc[mi][ni], 0, 0, 0);
    }

    // ---- epilogue: two 64-row halves
#pragma unroll
    for (int h = 0; h < 2; ++h) {
        __syncthreads();
        if (wrow == h) {
#pragma unroll
            for (int mi = 0; mi < 4; ++mi)
#pragma unroll
                for (int ni = 0; ni < 4; ++ni) {
                    const int col = wcol * 64 + ni * 16 + l15;
#pragma unroll
                    for (int r = 0; r < 4; ++r)
                        fscan[(mi * 16 + lq * 4 + r) * FSTR + col] =
                            acc[mi][ni][r];
                }
        }
        __syncthreads();
        const int rl = tid >> 2, q = tid & 3;
        const float* src = fscan + rl * FSTR + q * 32;
        const size_t gbase = (size_t)(m0 + h * 64 + rl) * 512 + n0 + q * 32;
#pragma unroll
        for (int c0 = 0; c0 < 8; ++c0) {
            int c = (c0 + 2 * q) & 7;            // bank-spread rotation
            f32x4 v  = *(const f32x4*)(src + c * 4);
            float4 xv = *(const float4*)&X[gbase + c * 4];
            f32x4 dv = *(const f32x4*)(dsum + q * 32 + c * 4);
            float4 o;
            o.x = v[0] + xv.x * dv[0];
            o.y = v[1] + xv.y * dv[1];
            o.z = v[2] + xv.z * dv[2];
            o.w = v[3] + xv.w * dv[3];
            *(float4*)&y[gbase + c * 4] = o;
        }
    }
}

// ---------------------------------------------------------------------------
// ws layout (bytes):
//  SB   : 0           (67,108,864)  [M][1024] bf16
//  Bm16 : 67,108,864  (1,048,576)
//  Cm16 : 68,157,440  (1,048,576)
//  abar : 69,206,016  (4,096)
//  apow : 69,210,112  (4,096)
//  X16  : 69,214,208  (33,554,432) -> end 102,768,640 (proven size)
//  init : 69,214,208  (4,194,304)   alias over X16 (dead after gemm1)
//  carry: d_out (first 4 MB; y fully overwritten by gemm2 afterwards)
extern "C" void kernel_launch(void* const* d_in, const int* in_sizes, int n_in,
                              void* d_out, int out_size, void* d_ws, size_t ws_size,
                              hipStream_t stream) {
    const float* x   = (const float*)d_in[0];
    const float* Lre = (const float*)d_in[1];
    const float* Lim = (const float*)d_in[2];
    const float* ldt = (const float*)d_in[3];
    const float* Bre = (const float*)d_in[4];
    const float* Bim = (const float*)d_in[5];
    const float* Cre = (const float*)d_in[6];
    const float* Cim = (const float*)d_in[7];
    const float* Dv  = (const float*)d_in[8];
    float* y = (float*)d_out;
    char* ws = (char*)d_ws;

    ushort_t* SB   = (ushort_t*)(ws);
    ushort_t* Bm16 = (ushort_t*)(ws + 67108864);
    ushort_t* Cm16 = (ushort_t*)(ws + 68157440);
    float* abar  = (float*)(ws + 69206016);
    float* apow  = (float*)(ws + 69210112);
    ushort_t* X16  = (ushort_t*)(ws + 69214208);
    float* initb = (float*)(ws + 69214208);     // alias (X16 dead after gemm1)
    float* carry = (float*)d_out;               // scratch in output buffer

    prep_conv<<<16384, 256, 0, stream>>>(x, X16, Lre, Lim, ldt, Bre, Bim,
                                         Cre, Cim, abar, apow, Bm16, Cm16);

    gemm1_mfma<<<2048, 256, 0, stream>>>(X16, Bm16, SB, abar, carry);

    scan_comb<<<B_SZ, 512, 0, stream>>>(carry, initb, apow);

    dim3 gs(B_SZ, NC);
    scan_final<<<gs, 512, 0, stream>>>(SB, abar, initb);

    gemm2_mfma<<<1024, 256, 0, stream>>>(SB, Cm16, y, x, Dv);
}